// Round 3
// baseline (1442.929 us; speedup 1.0000x reference)
//
#include <hip/hip_runtime.h>

#define NNODES 50000
#define NEDGES 800000
#define NG 50
#define PI_OVER_CUT 0.31415926535897931f
#define LN2 0.69314718055994531f

static_assert(NEDGES % 64 == 0, "edge tiling assumes E % 64 == 0");

typedef float f32x4 __attribute__((ext_vector_type(4)));
typedef float f32x2 __attribute__((ext_vector_type(2)));
typedef short s16x8 __attribute__((ext_vector_type(8)));

static __device__ __forceinline__ short f2bf(float f) {
  union { float f; unsigned u; } v; v.f = f;
  return (short)((v.u + 0x7fffu + ((v.u >> 16) & 1u)) >> 16);  // RNE
}

// softplus(x) - ln2, numerically stable
static __device__ __forceinline__ float sp_shift(float x) {
  return fmaxf(x, 0.f) + __logf(1.f + __expf(-fabsf(x))) - LN2;
}

// ---------------- K1: h1 = X @ W^T  (fp32, [N,128]x[128,128]) ----------------
__global__ __launch_bounds__(256) void cfconv_lin1(const float* __restrict__ X,
                                                   const float* __restrict__ W,
                                                   float* __restrict__ Y) {
  __shared__ __align__(16) float wT[128 * 68];   // wT[k][c] = W[c0+c][k], pad 68
  __shared__ __align__(16) float xs[64 * 132];   // xs[r][k], pad 132
  const int tid = threadIdx.x;
  const int row0 = (blockIdx.x >> 1) * 64;
  const int c0 = (blockIdx.x & 1) * 64;
  for (int i = tid; i < 64 * 128; i += 256) {
    int c = i >> 7, k = i & 127;
    wT[k * 68 + c] = W[(c0 + c) * 128 + k];
  }
  for (int i = tid; i < 64 * 128; i += 256) {
    int r = i >> 7, k = i & 127;
    int row = row0 + r;
    xs[r * 132 + k] = (row < NNODES) ? X[row * 128 + k] : 0.f;
  }
  __syncthreads();
  const int c4 = (tid & 15) * 4;
  const int r4 = (tid >> 4) * 4;
  f32x4 a0 = {}, a1 = {}, a2 = {}, a3 = {};
#pragma unroll 4
  for (int k = 0; k < 128; ++k) {
    f32x4 wv = *(const f32x4*)&wT[k * 68 + c4];
    a0 += wv * xs[(r4 + 0) * 132 + k];
    a1 += wv * xs[(r4 + 1) * 132 + k];
    a2 += wv * xs[(r4 + 2) * 132 + k];
    a3 += wv * xs[(r4 + 3) * 132 + k];
  }
  const int row = row0 + r4;
  if (row + 0 < NNODES) *(f32x4*)&Y[(row + 0) * 128 + c0 + c4] = a0;
  if (row + 1 < NNODES) *(f32x4*)&Y[(row + 1) * 128 + c0 + c4] = a1;
  if (row + 2 < NNODES) *(f32x4*)&Y[(row + 2) * 128 + c0 + c4] = a2;
  if (row + 3 < NNODES) *(f32x4*)&Y[(row + 3) * 128 + c0 + c4] = a3;
}

// ---------------- K3: out = (h1 + agg) @ W^T + b, in place on agg ------------
__global__ __launch_bounds__(256) void cfconv_lin2(const float* __restrict__ H1,
                                                   float* AO,  // agg in / out
                                                   const float* __restrict__ W,
                                                   const float* __restrict__ Bias) {
  __shared__ __align__(16) float wT[128 * 68];
  __shared__ __align__(16) float xs[64 * 132];
  const int tid = threadIdx.x;
  const int row0 = (blockIdx.x >> 1) * 64;
  const int c0 = (blockIdx.x & 1) * 64;
  for (int i = tid; i < 64 * 128; i += 256) {
    int c = i >> 7, k = i & 127;
    wT[k * 68 + c] = W[(c0 + c) * 128 + k];
  }
  for (int i = tid; i < 64 * 128; i += 256) {
    int r = i >> 7, k = i & 127;
    int row = row0 + r;
    xs[r * 132 + k] = (row < NNODES) ? (H1[row * 128 + k] + AO[row * 128 + k]) : 0.f;
  }
  __syncthreads();
  const int c4 = (tid & 15) * 4;
  const int r4 = (tid >> 4) * 4;
  f32x4 a0 = {}, a1 = {}, a2 = {}, a3 = {};
#pragma unroll 4
  for (int k = 0; k < 128; ++k) {
    f32x4 wv = *(const f32x4*)&wT[k * 68 + c4];
    a0 += wv * xs[(r4 + 0) * 132 + k];
    a1 += wv * xs[(r4 + 1) * 132 + k];
    a2 += wv * xs[(r4 + 2) * 132 + k];
    a3 += wv * xs[(r4 + 3) * 132 + k];
  }
  const f32x4 bv = *(const f32x4*)&Bias[c0 + c4];
  a0 += bv; a1 += bv; a2 += bv; a3 += bv;
  const int row = row0 + r4;
  if (row + 0 < NNODES) *(f32x4*)&AO[(row + 0) * 128 + c0 + c4] = a0;
  if (row + 1 < NNODES) *(f32x4*)&AO[(row + 1) * 128 + c0 + c4] = a1;
  if (row + 2 < NNODES) *(f32x4*)&AO[(row + 2) * 128 + c0 + c4] = a2;
  if (row + 3 < NNODES) *(f32x4*)&AO[(row + 3) * 128 + c0 + c4] = a3;
}

// ---------------- sort-by-dst machinery --------------------------------------
__global__ void k_hist(const int* __restrict__ ei, int* __restrict__ cnt) {
  int e = blockIdx.x * 256 + threadIdx.x;
  if (e < NEDGES) atomicAdd(&cnt[ei[e]], 1);
}

// single block of 1024: exclusive scan of cnt[50000] -> rp (row_ptr) and cursor
__global__ __launch_bounds__(1024) void k_scan(int* __restrict__ cnt /* in: counts, out: cursor */,
                                               int* __restrict__ rp) {
  __shared__ int part[1024];
  const int t = threadIdx.x;
  const int C = 49;  // 1024*49 = 50176 >= NNODES
  const int base = t * C;
  int s = 0;
  for (int i = 0; i < C; ++i) {
    int idx = base + i;
    if (idx < NNODES) s += cnt[idx];
  }
  part[t] = s;
  __syncthreads();
  for (int off = 1; off < 1024; off <<= 1) {
    int v = (t >= off) ? part[t - off] : 0;
    __syncthreads();
    part[t] += v;
    __syncthreads();
  }
  int pre = (t == 0) ? 0 : part[t - 1];  // exclusive prefix of this chunk
  for (int i = 0; i < C; ++i) {
    int idx = base + i;
    if (idx < NNODES) {
      int c = cnt[idx];
      rp[idx] = pre;
      cnt[idx] = pre;  // becomes the scatter cursor
      pre += c;
    }
  }
  if (t == 1023) rp[NNODES] = pre;  // == NEDGES
}

__global__ void k_scatter(const int* __restrict__ ei, int* __restrict__ cursor,
                          int* __restrict__ sorted) {
  int e = blockIdx.x * 256 + threadIdx.x;
  if (e < NEDGES) {
    int pos = atomicAdd(&cursor[ei[e]], 1);
    sorted[pos] = e;
  }
}

// ---------------- K2: one NODE per wave, zero atomics ------------------------
// Each wave owns node n: loops over its sorted edges in 16-edge MFMA chunks,
// accumulates per-filter column sums in registers, plain-stores agg[n].
__global__ __launch_bounds__(256) void cfconv_edge_sorted(
    const int* __restrict__ ei, const float* __restrict__ ew,
    const float* __restrict__ attr,
    const float* __restrict__ w1, const float* __restrict__ b1,
    const float* __restrict__ w2, const float* __restrict__ b2,
    const float* __restrict__ h1, const int* __restrict__ rp,
    const int* __restrict__ sorted, float* __restrict__ agg) {
  __shared__ __align__(16) short sB1[8192];    // W1^T frags: [s<2][t<8][lane][8]
  __shared__ __align__(16) short sB2[16384];   // W2^T frags: [s<4][t<8][lane][8]
  __shared__ __align__(16) short sA[4][1024];  // per-wave attr tile [16e][64g] bf16, swizzled
  __shared__ __align__(16) short sX[4][2048];  // per-wave X tile [16][128] bf16, swizzled
  __shared__ float sb1[128], sb2[128];
  const int tid = threadIdx.x;
  if (tid < 128) { sb1[tid] = b1[tid]; sb2[tid] = b2[tid]; }
  // B-operand fragment layout: lane l holds B[k=(l>>4)*8+j][n=(l&15)]
  for (int i = tid; i < 8192; i += 256) {
    int j = i & 7, l = (i >> 3) & 63, t = (i >> 9) & 7, s = i >> 12;
    int g = s * 32 + (l >> 4) * 8 + j;
    int f = t * 16 + (l & 15);
    sB1[i] = f2bf(g < NG ? w1[f * NG + g] : 0.f);
  }
  for (int i = tid; i < 16384; i += 256) {
    int j = i & 7, l = (i >> 3) & 63, t = (i >> 9) & 7, s = (i >> 12) & 3;
    int k = s * 32 + (l >> 4) * 8 + j;
    int f = t * 16 + (l & 15);
    sB2[i] = f2bf(w2[f * 128 + k]);
  }
  __syncthreads();   // weights ready; read-only from here on
  const int lane = tid & 63;
  const int wave = tid >> 6;
  const int lrow = lane & 15;
  const int lk = lane >> 4;
  const s16x8* B1 = (const s16x8*)sB1;
  const s16x8* B2 = (const s16x8*)sB2;
  char* sAw = (char*)sA[wave];
  char* sXw = (char*)sX[wave];
  const int gw0 = blockIdx.x * 4 + wave;
  const int gstride = gridDim.x * 4;
  for (int n = gw0; n < NNODES; n += gstride) {
    const int rbeg = rp[n], rend = rp[n + 1];
    float colsum[8] = {};
    for (int base = rbeg; base < rend; base += 16) {
      // ---- stage up to 16 attr rows (gathered via sorted[]) as bf16 --------
#pragma unroll
      for (int u = lane; u < 512; u += 64) {  // 16 rows x 32 bf16-pairs (pad g>=50)
        int er = u >> 5, gp = u & 31;
        int idx = base + er;
        f32x2 v = {0.f, 0.f};
        if (idx < rend && gp < 25) {
          int se = sorted[idx];
          v = *(const f32x2*)(attr + (size_t)se * NG + gp * 2);
        }
        unsigned pk = (unsigned short)f2bf(v.x) | ((unsigned)(unsigned short)f2bf(v.y) << 16);
        int a = (er * 128 + gp * 4) ^ ((er & 7) << 4);
        *(unsigned*)(sAw + a) = pk;
      }
      // ---- per-row meta + h1 gathers (issued early, hide under MFMA) -------
      int src[4]; float cwv[4];
#pragma unroll
      for (int r = 0; r < 4; ++r) {
        int idx = base + lk * 4 + r;
        if (idx < rend) {
          int se = sorted[idx];
          src[r] = ei[NEDGES + se];
          cwv[r] = 0.5f * (__cosf(ew[se] * PI_OVER_CUT) + 1.f);
        } else { src[r] = 0; cwv[r] = 0.f; }
      }
      float hv[8][4];
#pragma unroll
      for (int t = 0; t < 8; ++t)
#pragma unroll
        for (int r = 0; r < 4; ++r)
          hv[t][r] = h1[(size_t)src[r] * 128 + t * 16 + lrow];
      // ---- stage 1: X = attr @ W1^T ----
      f32x4 acc[8] = {};
#pragma unroll
      for (int s = 0; s < 2; ++s) {
        int ab = (lrow * 128 + s * 64 + lk * 16) ^ ((lrow & 7) << 4);
        s16x8 av = *(const s16x8*)(sAw + ab);
#pragma unroll
        for (int t = 0; t < 8; ++t)
          acc[t] = __builtin_amdgcn_mfma_f32_16x16x32_bf16(av, B1[(s * 8 + t) * 64 + lane], acc[t], 0, 0, 0);
      }
      // softplus, write wave-private X tile (bf16, swizzled)
#pragma unroll
      for (int t = 0; t < 8; ++t) {
        int f = t * 16 + lrow;
        float bb = sb1[f];
#pragma unroll
        for (int r = 0; r < 4; ++r) {
          int row = lk * 4 + r;
          float v = sp_shift(acc[t][r] + bb);
          int a = (row * 256 + f * 2) ^ ((row & 7) << 4);
          *(short*)(sXw + a) = f2bf(v);
        }
      }
      // ---- stage 2: S = X @ W2^T ----
      f32x4 acc2[8] = {};
#pragma unroll
      for (int s = 0; s < 4; ++s) {
        int ab = (lrow * 256 + s * 64 + lk * 16) ^ ((lrow & 7) << 4);
        s16x8 av = *(const s16x8*)(sXw + ab);
#pragma unroll
        for (int t = 0; t < 8; ++t)
          acc2[t] = __builtin_amdgcn_mfma_f32_16x16x32_bf16(av, B2[(s * 8 + t) * 64 + lane], acc2[t], 0, 0, 0);
      }
      // ---- accumulate this chunk's messages into per-node column sums ------
#pragma unroll
      for (int t = 0; t < 8; ++t) {
        float bb = sb2[t * 16 + lrow];
#pragma unroll
        for (int r = 0; r < 4; ++r)
          colsum[t] += sp_shift(acc2[t][r] + bb) * cwv[r] * hv[t][r];
      }
    }
    // ---- cross-lane reduce over the 4 row-groups; plain store (no atomics) --
#pragma unroll
    for (int t = 0; t < 8; ++t) {
      float v = colsum[t];
      v += __shfl_xor(v, 16);
      v += __shfl_xor(v, 32);
      if (lk == 0) agg[(size_t)n * 128 + t * 16 + lrow] = v;
    }
  }
}

// ---------------- fallback (round-2 atomic path) if ws is too small ----------
__global__ __launch_bounds__(256) void cfconv_edge_atomic(
    const int* __restrict__ ei, const float* __restrict__ ew,
    const float* __restrict__ attr,
    const float* __restrict__ w1, const float* __restrict__ b1,
    const float* __restrict__ w2, const float* __restrict__ b2,
    const float* __restrict__ h1, float* __restrict__ agg) {
  __shared__ __align__(16) short sB1[8192];
  __shared__ __align__(16) short sB2[16384];
  __shared__ __align__(16) short sA[4][1024];
  __shared__ __align__(16) short sX[4][2048];
  __shared__ float sb1[128], sb2[128];
  const int tid = threadIdx.x;
  if (tid < 128) { sb1[tid] = b1[tid]; sb2[tid] = b2[tid]; }
  for (int i = tid; i < 8192; i += 256) {
    int j = i & 7, l = (i >> 3) & 63, t = (i >> 9) & 7, s = i >> 12;
    int g = s * 32 + (l >> 4) * 8 + j;
    int f = t * 16 + (l & 15);
    sB1[i] = f2bf(g < NG ? w1[f * NG + g] : 0.f);
  }
  for (int i = tid; i < 16384; i += 256) {
    int j = i & 7, l = (i >> 3) & 63, t = (i >> 9) & 7, s = (i >> 12) & 3;
    int k = s * 32 + (l >> 4) * 8 + j;
    int f = t * 16 + (l & 15);
    sB2[i] = f2bf(w2[f * 128 + k]);
  }
  __syncthreads();
  const int lane = tid & 63;
  const int wave = tid >> 6;
  const int lrow = lane & 15;
  const int lk = lane >> 4;
  const s16x8* B1 = (const s16x8*)sB1;
  const s16x8* B2 = (const s16x8*)sB2;
  char* sAw = (char*)sA[wave];
  char* sXw = (char*)sX[wave];
  const int nwt = NEDGES / 16;
  const int gw0 = blockIdx.x * 4 + wave;
  const int gstride = gridDim.x * 4;
  for (int wt = gw0; wt < nwt; wt += gstride) {
    const int e0 = wt * 16;
    int dst[4], src[4];
    float cw[4];
#pragma unroll
    for (int r = 0; r < 4; ++r) {
      int e = e0 + lk * 4 + r;
      dst[r] = ei[e];
      src[r] = ei[NEDGES + e];
      cw[r] = 0.5f * (__cosf(ew[e] * PI_OVER_CUT) + 1.f);
    }
    float hv[8][4];
#pragma unroll
    for (int t = 0; t < 8; ++t)
#pragma unroll
      for (int r = 0; r < 4; ++r)
        hv[t][r] = h1[(size_t)src[r] * 128 + t * 16 + lrow];
    const float* arow = attr + (size_t)e0 * NG;
#pragma unroll
    for (int u = lane; u < 512; u += 64) {
      int e = u >> 5, gp = u & 31;
      f32x2 v = {0.f, 0.f};
      if (gp < 25) v = *(const f32x2*)(arow + e * NG + gp * 2);
      unsigned pk = (unsigned short)f2bf(v.x) | ((unsigned)(unsigned short)f2bf(v.y) << 16);
      int a = (e * 128 + gp * 4) ^ ((e & 7) << 4);
      *(unsigned*)(sAw + a) = pk;
    }
    f32x4 acc[8] = {};
#pragma unroll
    for (int s = 0; s < 2; ++s) {
      int ab = (lrow * 128 + s * 64 + lk * 16) ^ ((lrow & 7) << 4);
      s16x8 av = *(const s16x8*)(sAw + ab);
#pragma unroll
      for (int t = 0; t < 8; ++t)
        acc[t] = __builtin_amdgcn_mfma_f32_16x16x32_bf16(av, B1[(s * 8 + t) * 64 + lane], acc[t], 0, 0, 0);
    }
#pragma unroll
    for (int t = 0; t < 8; ++t) {
      int f = t * 16 + lrow;
      float bb = sb1[f];
#pragma unroll
      for (int r = 0; r < 4; ++r) {
        int row = lk * 4 + r;
        float v = sp_shift(acc[t][r] + bb);
        int a = (row * 256 + f * 2) ^ ((row & 7) << 4);
        *(short*)(sXw + a) = f2bf(v);
      }
    }
    f32x4 acc2[8] = {};
#pragma unroll
    for (int s = 0; s < 4; ++s) {
      int ab = (lrow * 256 + s * 64 + lk * 16) ^ ((lrow & 7) << 4);
      s16x8 av = *(const s16x8*)(sXw + ab);
#pragma unroll
      for (int t = 0; t < 8; ++t)
        acc2[t] = __builtin_amdgcn_mfma_f32_16x16x32_bf16(av, B2[(s * 8 + t) * 64 + lane], acc2[t], 0, 0, 0);
    }
#pragma unroll
    for (int t = 0; t < 8; ++t) {
      int f = t * 16 + lrow;
      float bb = sb2[f];
#pragma unroll
      for (int r = 0; r < 4; ++r) {
        float Wv = sp_shift(acc2[t][r] + bb) * cw[r];
        atomicAdd(&agg[(size_t)dst[r] * 128 + f], Wv * hv[t][r]);
      }
    }
  }
}

extern "C" void kernel_launch(void* const* d_in, const int* in_sizes, int n_in,
                              void* d_out, int out_size, void* d_ws, size_t ws_size,
                              hipStream_t stream) {
  const float* h      = (const float*)d_in[0];
  const int*   ei     = (const int*)d_in[1];
  const float* ew     = (const float*)d_in[2];
  const float* attr   = (const float*)d_in[3];
  const float* lin1_w = (const float*)d_in[4];
  const float* nn_w1  = (const float*)d_in[5];
  const float* nn_b1  = (const float*)d_in[6];
  const float* nn_w2  = (const float*)d_in[7];
  const float* nn_b2  = (const float*)d_in[8];
  const float* lin2_w = (const float*)d_in[9];
  const float* lin2_b = (const float*)d_in[10];
  float* out = (float*)d_out;   // agg accumulator, then final output

  const int rb2 = ((NNODES + 63) / 64) * 2;
  // ws layout: rp[50001] | cursor[50000] | sorted[800000] | pad | h1[50000*128]
  const size_t h1_off = 3600128;  // bytes, 128B-aligned after 900001 ints
  const size_t needed = h1_off + (size_t)NNODES * 128 * sizeof(float);

  if (ws_size >= needed) {
    int* rp      = (int*)d_ws;
    int* cursor  = rp + 50004;
    int* sorted  = rp + 100004;
    float* h1    = (float*)((char*)d_ws + h1_off);
    hipMemsetAsync(cursor, 0, NNODES * sizeof(int), stream);
    k_hist<<<(NEDGES + 255) / 256, 256, 0, stream>>>(ei, cursor);
    k_scan<<<1, 1024, 0, stream>>>(cursor, rp);
    k_scatter<<<(NEDGES + 255) / 256, 256, 0, stream>>>(ei, cursor, sorted);
    cfconv_lin1<<<rb2, 256, 0, stream>>>(h, lin1_w, h1);
    cfconv_edge_sorted<<<512, 256, 0, stream>>>(ei, ew, attr, nn_w1, nn_b1,
                                                nn_w2, nn_b2, h1, rp, sorted, out);
    cfconv_lin2<<<rb2, 256, 0, stream>>>(h1, out, lin2_w, lin2_b);
  } else {
    float* h1 = (float*)d_ws;
    hipMemsetAsync(out, 0, (size_t)NNODES * 128 * sizeof(float), stream);
    cfconv_lin1<<<rb2, 256, 0, stream>>>(h, lin1_w, h1);
    cfconv_edge_atomic<<<512, 256, 0, stream>>>(ei, ew, attr, nn_w1, nn_b1,
                                                nn_w2, nn_b2, h1, out);
    cfconv_lin2<<<rb2, 256, 0, stream>>>(h1, out, lin2_w, lin2_b);
  }
}

// Round 4
// 640.118 us; speedup vs baseline: 2.2542x; 2.2542x over previous
//
#include <hip/hip_runtime.h>

#define NNODES 50000
#define NEDGES 800000
#define NG 50
#define PI_OVER_CUT 0.31415926535897931f
#define LN2 0.69314718055994531f

static_assert(NEDGES % 16 == 0, "edge tiling assumes E % 16 == 0");
#define NTILES (NEDGES / 16)

typedef float f32x4 __attribute__((ext_vector_type(4)));
typedef float f32x2 __attribute__((ext_vector_type(2)));
typedef short s16x8 __attribute__((ext_vector_type(8)));

static __device__ __forceinline__ short f2bf(float f) {
  union { float f; unsigned u; } v; v.f = f;
  return (short)((v.u + 0x7fffu + ((v.u >> 16) & 1u)) >> 16);  // RNE
}

// softplus(x) - ln2, numerically stable
static __device__ __forceinline__ float sp_shift(float x) {
  return fmaxf(x, 0.f) + __logf(1.f + __expf(-fabsf(x))) - LN2;
}

// ---------------- K1: h1 = X @ W^T  (fp32, [N,128]x[128,128]) ----------------
__global__ __launch_bounds__(256) void cfconv_lin1(const float* __restrict__ X,
                                                   const float* __restrict__ W,
                                                   float* __restrict__ Y) {
  __shared__ __align__(16) float wT[128 * 68];   // wT[k][c] = W[c0+c][k], pad 68
  __shared__ __align__(16) float xs[64 * 132];   // xs[r][k], pad 132
  const int tid = threadIdx.x;
  const int row0 = (blockIdx.x >> 1) * 64;
  const int c0 = (blockIdx.x & 1) * 64;
  for (int i = tid; i < 64 * 128; i += 256) {
    int c = i >> 7, k = i & 127;
    wT[k * 68 + c] = W[(c0 + c) * 128 + k];
  }
  for (int i = tid; i < 64 * 128; i += 256) {
    int r = i >> 7, k = i & 127;
    int row = row0 + r;
    xs[r * 132 + k] = (row < NNODES) ? X[row * 128 + k] : 0.f;
  }
  __syncthreads();
  const int c4 = (tid & 15) * 4;
  const int r4 = (tid >> 4) * 4;
  f32x4 a0 = {}, a1 = {}, a2 = {}, a3 = {};
#pragma unroll 4
  for (int k = 0; k < 128; ++k) {
    f32x4 wv = *(const f32x4*)&wT[k * 68 + c4];
    a0 += wv * xs[(r4 + 0) * 132 + k];
    a1 += wv * xs[(r4 + 1) * 132 + k];
    a2 += wv * xs[(r4 + 2) * 132 + k];
    a3 += wv * xs[(r4 + 3) * 132 + k];
  }
  const int row = row0 + r4;
  if (row + 0 < NNODES) *(f32x4*)&Y[(row + 0) * 128 + c0 + c4] = a0;
  if (row + 1 < NNODES) *(f32x4*)&Y[(row + 1) * 128 + c0 + c4] = a1;
  if (row + 2 < NNODES) *(f32x4*)&Y[(row + 2) * 128 + c0 + c4] = a2;
  if (row + 3 < NNODES) *(f32x4*)&Y[(row + 3) * 128 + c0 + c4] = a3;
}

// ------- K3: out = (h1 + agg) @ W^T + b. Full-width blocks: each block owns
// 64 rows end-to-end (reads its rows, syncs, writes its rows) -> no cross-block
// read/write aliasing on AO. ----------------------------------------------------
__global__ __launch_bounds__(256) void cfconv_lin2(const float* __restrict__ H1,
                                                   float* AO,  // agg in / out (self rows only)
                                                   const float* __restrict__ W,
                                                   const float* __restrict__ Bias) {
  __shared__ __align__(16) float wT[128 * 132];  // wT[k][c], full 128 cols, pad 132
  __shared__ __align__(16) float xs[64 * 132];   // xs[r][k]
  const int tid = threadIdx.x;
  const int row0 = blockIdx.x * 64;
  for (int i = tid; i < 128 * 128; i += 256) {
    int c = i >> 7, k = i & 127;
    wT[k * 132 + c] = W[c * 128 + k];
  }
  for (int i = tid; i < 64 * 128; i += 256) {
    int r = i >> 7, k = i & 127;
    int row = row0 + r;
    xs[r * 132 + k] = (row < NNODES) ? (H1[(size_t)row * 128 + k] + AO[(size_t)row * 128 + k]) : 0.f;
  }
  __syncthreads();
  const int c8 = (tid & 15) * 8;
  const int r4 = (tid >> 4) * 4;
  f32x4 a[4][2] = {};
#pragma unroll 2
  for (int k = 0; k < 128; ++k) {
    f32x4 w0 = *(const f32x4*)&wT[k * 132 + c8];
    f32x4 w1 = *(const f32x4*)&wT[k * 132 + c8 + 4];
#pragma unroll
    for (int r = 0; r < 4; ++r) {
      float x = xs[(r4 + r) * 132 + k];
      a[r][0] += w0 * x;
      a[r][1] += w1 * x;
    }
  }
  const f32x4 b0 = *(const f32x4*)&Bias[c8];
  const f32x4 b1 = *(const f32x4*)&Bias[c8 + 4];
#pragma unroll
  for (int r = 0; r < 4; ++r) {
    int row = row0 + r4 + r;
    if (row < NNODES) {
      *(f32x4*)&AO[(size_t)row * 128 + c8]     = a[r][0] + b0;
      *(f32x4*)&AO[(size_t)row * 128 + c8 + 4] = a[r][1] + b1;
    }
  }
}

// ---------------- sort-by-dst machinery --------------------------------------
__global__ void k_hist(const int* __restrict__ ei, int* __restrict__ cnt) {
  int e = blockIdx.x * 256 + threadIdx.x;
  if (e < NEDGES) atomicAdd(&cnt[ei[e]], 1);
}

// single block of 1024: exclusive scan of cnt[50000] in place (becomes cursor)
__global__ __launch_bounds__(1024) void k_scan(int* __restrict__ cnt) {
  __shared__ int part[1024];
  const int t = threadIdx.x;
  const int C = 49;  // 1024*49 = 50176 >= NNODES
  const int base = t * C;
  int s = 0;
  for (int i = 0; i < C; ++i) {
    int idx = base + i;
    if (idx < NNODES) s += cnt[idx];
  }
  part[t] = s;
  __syncthreads();
  for (int off = 1; off < 1024; off <<= 1) {
    int v = (t >= off) ? part[t - off] : 0;
    __syncthreads();
    part[t] += v;
    __syncthreads();
  }
  int pre = (t == 0) ? 0 : part[t - 1];  // exclusive prefix of this chunk
  for (int i = 0; i < C; ++i) {
    int idx = base + i;
    if (idx < NNODES) {
      int c = cnt[idx];
      cnt[idx] = pre;  // cursor
      pre += c;
    }
  }
}

__global__ void k_scatter(const int* __restrict__ ei, int* __restrict__ cursor,
                          int* __restrict__ sorted) {
  int e = blockIdx.x * 256 + threadIdx.x;
  if (e < NEDGES) {
    int pos = atomicAdd(&cursor[ei[e]], 1);
    sorted[pos] = e;
  }
}

// ---------------- K2: edge-parallel over dst-sorted tiles --------------------
// 16 consecutive sorted edges per wave-tile; dsts within a tile are
// non-decreasing -> exact segmented reduction cuts atomics ~8x.
__global__ __launch_bounds__(256) void cfconv_edge_sorted(
    const int* __restrict__ ei, const float* __restrict__ ew,
    const float* __restrict__ attr,
    const float* __restrict__ w1, const float* __restrict__ b1,
    const float* __restrict__ w2, const float* __restrict__ b2,
    const float* __restrict__ h1, const int* __restrict__ sorted,
    float* __restrict__ agg) {
  __shared__ __align__(16) short sB1[8192];    // W1^T frags: [s<2][t<8][lane][8]
  __shared__ __align__(16) short sB2[16384];   // W2^T frags: [s<4][t<8][lane][8]
  __shared__ __align__(16) short sA[4][1024];  // per-wave attr tile [16e][64g] bf16, swizzled
  __shared__ __align__(16) short sX[4][2048];  // per-wave X tile [16][128] bf16, swizzled
  __shared__ float sb1[128], sb2[128];
  const int tid = threadIdx.x;
  if (tid < 128) { sb1[tid] = b1[tid]; sb2[tid] = b2[tid]; }
  // B-operand fragment layout: lane l holds B[k=(l>>4)*8+j][n=(l&15)]
  for (int i = tid; i < 8192; i += 256) {
    int j = i & 7, l = (i >> 3) & 63, t = (i >> 9) & 7, s = i >> 12;
    int g = s * 32 + (l >> 4) * 8 + j;
    int f = t * 16 + (l & 15);
    sB1[i] = f2bf(g < NG ? w1[f * NG + g] : 0.f);
  }
  for (int i = tid; i < 16384; i += 256) {
    int j = i & 7, l = (i >> 3) & 63, t = (i >> 9) & 7, s = (i >> 12) & 3;
    int k = s * 32 + (l >> 4) * 8 + j;
    int f = t * 16 + (l & 15);
    sB2[i] = f2bf(w2[f * 128 + k]);
  }
  __syncthreads();   // weights ready; read-only from here on
  const int lane = tid & 63;
  const int wave = tid >> 6;
  const int lrow = lane & 15;
  const int lk = lane >> 4;
  const s16x8* B1 = (const s16x8*)sB1;
  const s16x8* B2 = (const s16x8*)sB2;
  char* sAw = (char*)sA[wave];
  char* sXw = (char*)sX[wave];
  const int gw0 = blockIdx.x * 4 + wave;
  const int gstride = gridDim.x * 4;
  for (int tile = gw0; tile < NTILES; tile += gstride) {
    const int t16 = tile * 16;
    // ---- per-edge meta (sorted order) + h1 gathers, issued early -----------
    int se[4], dstv[4], srcv[4];
    float cwv[4];
#pragma unroll
    for (int r = 0; r < 4; ++r) {
      se[r] = sorted[t16 + lk * 4 + r];
      dstv[r] = ei[se[r]];
      srcv[r] = ei[NEDGES + se[r]];
      cwv[r] = 0.5f * (__cosf(ew[se[r]] * PI_OVER_CUT) + 1.f);
    }
    float hv[8][4];
#pragma unroll
    for (int t = 0; t < 8; ++t)
#pragma unroll
      for (int r = 0; r < 4; ++r)
        hv[t][r] = h1[(size_t)srcv[r] * 128 + t * 16 + lrow];
    // ---- stage 16 attr rows (gathered) as bf16, swizzled -------------------
#pragma unroll
    for (int u = lane; u < 512; u += 64) {   // 16 rows x 32 bf16-pairs (pad g>=50)
      int er = u >> 5, gp = u & 31;
      int see = sorted[t16 + er];
      f32x2 v = {0.f, 0.f};
      if (gp < 25) v = *(const f32x2*)(attr + (size_t)see * NG + gp * 2);
      unsigned pk = (unsigned short)f2bf(v.x) | ((unsigned)(unsigned short)f2bf(v.y) << 16);
      int a = (er * 128 + gp * 4) ^ ((er & 7) << 4);
      *(unsigned*)(sAw + a) = pk;
    }
    // ---- stage 1: X = attr @ W1^T ----
    f32x4 acc[8] = {};
#pragma unroll
    for (int s = 0; s < 2; ++s) {
      int ab = (lrow * 128 + s * 64 + lk * 16) ^ ((lrow & 7) << 4);
      s16x8 av = *(const s16x8*)(sAw + ab);
#pragma unroll
      for (int t = 0; t < 8; ++t)
        acc[t] = __builtin_amdgcn_mfma_f32_16x16x32_bf16(av, B1[(s * 8 + t) * 64 + lane], acc[t], 0, 0, 0);
    }
    // softplus, write wave-private X tile (bf16, swizzled)
#pragma unroll
    for (int t = 0; t < 8; ++t) {
      int f = t * 16 + lrow;
      float bb = sb1[f];
#pragma unroll
      for (int r = 0; r < 4; ++r) {
        int row = lk * 4 + r;
        float v = sp_shift(acc[t][r] + bb);
        int a = (row * 256 + f * 2) ^ ((row & 7) << 4);
        *(short*)(sXw + a) = f2bf(v);
      }
    }
    // ---- stage 2: S = X @ W2^T ----
    f32x4 acc2[8] = {};
#pragma unroll
    for (int s = 0; s < 4; ++s) {
      int ab = (lrow * 256 + s * 64 + lk * 16) ^ ((lrow & 7) << 4);
      s16x8 av = *(const s16x8*)(sXw + ab);
#pragma unroll
      for (int t = 0; t < 8; ++t)
        acc2[t] = __builtin_amdgcn_mfma_f32_16x16x32_bf16(av, B2[(s * 8 + t) * 64 + lane], acc2[t], 0, 0, 0);
    }
    // ---- segmented-reduction epilogue (dsts non-decreasing in tile) --------
    // t-invariant structure:
    const int d0 = dstv[0], d3 = dstv[3];
    const bool b1f = dstv[1] != d0, b2f = dstv[2] != dstv[1], b3f = d3 != dstv[2];
    const bool allsame = !(b1f | b2f | b3f);
    const int next_head = __shfl(d0, (lane + 16) & 63);
    const bool tor = (lk < 3) && (next_head == d3);          // tail continues right
    const int td0 = __shfl(d3, lrow);                        // tail dst of lk=0..2 groups
    const int td1 = __shfl(d3, lrow + 16);
    const int td2 = __shfl(d3, lrow + 32);
    const bool m0 = (lk >= 1) && (td0 == d0);
    const bool m1 = (lk >= 2) && (td1 == d0);
    const bool m2 = (lk >= 3) && (td2 == d0);
    const bool emit_head = !(allsame && tor);
    const bool emit_tail = (!allsame) && !tor;
    const bool mid1 = b1f && b2f, mid2 = b2f && b3f, mid12 = b1f && (!b2f) && b3f;
#pragma unroll
    for (int t = 0; t < 8; ++t) {
      int f = t * 16 + lrow;
      float bb = sb2[f];
      float v0 = sp_shift(acc2[t][0] + bb) * cwv[0] * hv[t][0];
      float v1 = sp_shift(acc2[t][1] + bb) * cwv[1] * hv[t][1];
      float v2 = sp_shift(acc2[t][2] + bb) * cwv[2] * hv[t][2];
      float v3 = sp_shift(acc2[t][3] + bb) * cwv[3] * hv[t][3];
      float head_sum = v0 + (b1f ? 0.f : v1 + (b2f ? 0.f : v2 + (b3f ? 0.f : v3)));
      float tail_sum = v3 + (b3f ? 0.f : v2 + (b2f ? 0.f : v1 + (b1f ? 0.f : v0)));
      float ts0 = __shfl(tail_sum, lrow);
      float ts1 = __shfl(tail_sum, lrow + 16);
      float ts2 = __shfl(tail_sum, lrow + 32);
      float carry = (m0 ? ts0 : 0.f) + (m1 ? ts1 : 0.f) + (m2 ? ts2 : 0.f);
      if (emit_head) atomicAdd(&agg[(size_t)d0 * 128 + f], head_sum + carry);
      if (emit_tail) atomicAdd(&agg[(size_t)d3 * 128 + f], tail_sum);
      if (mid1) atomicAdd(&agg[(size_t)dstv[1] * 128 + f], v1);
      if (mid2) atomicAdd(&agg[(size_t)dstv[2] * 128 + f], v2);
      if (mid12) atomicAdd(&agg[(size_t)dstv[1] * 128 + f], v1 + v2);
    }
  }
}

// ---------------- fallback (round-2 atomic path) if ws is too small ----------
__global__ __launch_bounds__(256) void cfconv_edge_atomic(
    const int* __restrict__ ei, const float* __restrict__ ew,
    const float* __restrict__ attr,
    const float* __restrict__ w1, const float* __restrict__ b1,
    const float* __restrict__ w2, const float* __restrict__ b2,
    const float* __restrict__ h1, float* __restrict__ agg) {
  __shared__ __align__(16) short sB1[8192];
  __shared__ __align__(16) short sB2[16384];
  __shared__ __align__(16) short sA[4][1024];
  __shared__ __align__(16) short sX[4][2048];
  __shared__ float sb1[128], sb2[128];
  const int tid = threadIdx.x;
  if (tid < 128) { sb1[tid] = b1[tid]; sb2[tid] = b2[tid]; }
  for (int i = tid; i < 8192; i += 256) {
    int j = i & 7, l = (i >> 3) & 63, t = (i >> 9) & 7, s = i >> 12;
    int g = s * 32 + (l >> 4) * 8 + j;
    int f = t * 16 + (l & 15);
    sB1[i] = f2bf(g < NG ? w1[f * NG + g] : 0.f);
  }
  for (int i = tid; i < 16384; i += 256) {
    int j = i & 7, l = (i >> 3) & 63, t = (i >> 9) & 7, s = (i >> 12) & 3;
    int k = s * 32 + (l >> 4) * 8 + j;
    int f = t * 16 + (l & 15);
    sB2[i] = f2bf(w2[f * 128 + k]);
  }
  __syncthreads();
  const int lane = tid & 63;
  const int wave = tid >> 6;
  const int lrow = lane & 15;
  const int lk = lane >> 4;
  const s16x8* B1 = (const s16x8*)sB1;
  const s16x8* B2 = (const s16x8*)sB2;
  char* sAw = (char*)sA[wave];
  char* sXw = (char*)sX[wave];
  const int nwt = NEDGES / 16;
  const int gw0 = blockIdx.x * 4 + wave;
  const int gstride = gridDim.x * 4;
  for (int wt = gw0; wt < nwt; wt += gstride) {
    const int e0 = wt * 16;
    int dst[4], src[4];
    float cw[4];
#pragma unroll
    for (int r = 0; r < 4; ++r) {
      int e = e0 + lk * 4 + r;
      dst[r] = ei[e];
      src[r] = ei[NEDGES + e];
      cw[r] = 0.5f * (__cosf(ew[e] * PI_OVER_CUT) + 1.f);
    }
    float hv[8][4];
#pragma unroll
    for (int t = 0; t < 8; ++t)
#pragma unroll
      for (int r = 0; r < 4; ++r)
        hv[t][r] = h1[(size_t)src[r] * 128 + t * 16 + lrow];
    const float* arow = attr + (size_t)e0 * NG;
#pragma unroll
    for (int u = lane; u < 512; u += 64) {
      int e = u >> 5, gp = u & 31;
      f32x2 v = {0.f, 0.f};
      if (gp < 25) v = *(const f32x2*)(arow + e * NG + gp * 2);
      unsigned pk = (unsigned short)f2bf(v.x) | ((unsigned)(unsigned short)f2bf(v.y) << 16);
      int a = (e * 128 + gp * 4) ^ ((e & 7) << 4);
      *(unsigned*)(sAw + a) = pk;
    }
    f32x4 acc[8] = {};
#pragma unroll
    for (int s = 0; s < 2; ++s) {
      int ab = (lrow * 128 + s * 64 + lk * 16) ^ ((lrow & 7) << 4);
      s16x8 av = *(const s16x8*)(sAw + ab);
#pragma unroll
      for (int t = 0; t < 8; ++t)
        acc[t] = __builtin_amdgcn_mfma_f32_16x16x32_bf16(av, B1[(s * 8 + t) * 64 + lane], acc[t], 0, 0, 0);
    }
#pragma unroll
    for (int t = 0; t < 8; ++t) {
      int f = t * 16 + lrow;
      float bb = sb1[f];
#pragma unroll
      for (int r = 0; r < 4; ++r) {
        int row = lk * 4 + r;
        float v = sp_shift(acc[t][r] + bb);
        int a = (row * 256 + f * 2) ^ ((row & 7) << 4);
        *(short*)(sXw + a) = f2bf(v);
      }
    }
    f32x4 acc2[8] = {};
#pragma unroll
    for (int s = 0; s < 4; ++s) {
      int ab = (lrow * 256 + s * 64 + lk * 16) ^ ((lrow & 7) << 4);
      s16x8 av = *(const s16x8*)(sXw + ab);
#pragma unroll
      for (int t = 0; t < 8; ++t)
        acc2[t] = __builtin_amdgcn_mfma_f32_16x16x32_bf16(av, B2[(s * 8 + t) * 64 + lane], acc2[t], 0, 0, 0);
    }
#pragma unroll
    for (int t = 0; t < 8; ++t) {
      int f = t * 16 + lrow;
      float bb = sb2[f];
#pragma unroll
      for (int r = 0; r < 4; ++r) {
        float Wv = sp_shift(acc2[t][r] + bb) * cw[r];
        atomicAdd(&agg[(size_t)dst[r] * 128 + f], Wv * hv[t][r]);
      }
    }
  }
}

extern "C" void kernel_launch(void* const* d_in, const int* in_sizes, int n_in,
                              void* d_out, int out_size, void* d_ws, size_t ws_size,
                              hipStream_t stream) {
  const float* h      = (const float*)d_in[0];
  const int*   ei     = (const int*)d_in[1];
  const float* ew     = (const float*)d_in[2];
  const float* attr   = (const float*)d_in[3];
  const float* lin1_w = (const float*)d_in[4];
  const float* nn_w1  = (const float*)d_in[5];
  const float* nn_b1  = (const float*)d_in[6];
  const float* nn_w2  = (const float*)d_in[7];
  const float* nn_b2  = (const float*)d_in[8];
  const float* lin2_w = (const float*)d_in[9];
  const float* lin2_b = (const float*)d_in[10];
  float* out = (float*)d_out;   // agg accumulator, then final output

  const int rb2 = ((NNODES + 63) / 64) * 2;      // lin1 grid (split-col, no alias)
  const int rbF = (NNODES + 63) / 64;            // lin2 grid (full-width)

  // ws layout: cnt/cursor[50000] | sorted[800000] | pad | h1[50000*128]
  const size_t sorted_off = 50000 * 4;                       // 200000
  const size_t h1_off     = (sorted_off + 800000 * 4 + 127) & ~(size_t)127;  // 3400064->3400192
  const size_t needed     = h1_off + (size_t)NNODES * 128 * sizeof(float);

  if (ws_size >= needed) {
    int* cnt    = (int*)d_ws;
    int* sorted = (int*)((char*)d_ws + sorted_off);
    float* h1   = (float*)((char*)d_ws + h1_off);
    hipMemsetAsync(cnt, 0, 50000 * sizeof(int), stream);
    hipMemsetAsync(out, 0, (size_t)NNODES * 128 * sizeof(float), stream);
    k_hist<<<(NEDGES + 255) / 256, 256, 0, stream>>>(ei, cnt);
    k_scan<<<1, 1024, 0, stream>>>(cnt);
    k_scatter<<<(NEDGES + 255) / 256, 256, 0, stream>>>(ei, cnt, sorted);
    cfconv_lin1<<<rb2, 256, 0, stream>>>(h, lin1_w, h1);
    cfconv_edge_sorted<<<512, 256, 0, stream>>>(ei, ew, attr, nn_w1, nn_b1,
                                                nn_w2, nn_b2, h1, sorted, out);
    cfconv_lin2<<<rbF, 256, 0, stream>>>(h1, out, lin2_w, lin2_b);
  } else {
    float* h1 = (float*)d_ws;
    hipMemsetAsync(out, 0, (size_t)NNODES * 128 * sizeof(float), stream);
    cfconv_lin1<<<rb2, 256, 0, stream>>>(h, lin1_w, h1);
    cfconv_edge_atomic<<<512, 256, 0, stream>>>(ei, ew, attr, nn_w1, nn_b1,
                                                nn_w2, nn_b2, h1, out);
    cfconv_lin2<<<rbF, 256, 0, stream>>>(h1, out, lin2_w, lin2_b);
  }
}

// Round 5
// 464.640 us; speedup vs baseline: 3.1055x; 1.3777x over previous
//
#include <hip/hip_runtime.h>

#define NNODES 50000
#define NEDGES 800000
#define NG 50
#define PI_OVER_CUT 0.31415926535897931f
#define LN2 0.69314718055994531f

static_assert(NEDGES % 16 == 0, "edge tiling assumes E % 16 == 0");
#define NTILES (NEDGES / 16)
#define SCAN_N 50176            // 196 * 256 >= NNODES
#define SCAN_BLK 196

typedef float f32x4 __attribute__((ext_vector_type(4)));
typedef float f32x2 __attribute__((ext_vector_type(2)));
typedef short s16x8 __attribute__((ext_vector_type(8)));

static __device__ __forceinline__ short f2bf(float f) {
  union { float f; unsigned u; } v; v.f = f;
  return (short)((v.u + 0x7fffu + ((v.u >> 16) & 1u)) >> 16);  // RNE
}

// softplus(x) - ln2, numerically stable
static __device__ __forceinline__ float sp_shift(float x) {
  return fmaxf(x, 0.f) + __logf(1.f + __expf(-fabsf(x))) - LN2;
}

// ---------------- K1: h1 = X @ W^T  (fp32, [N,128]x[128,128]) ----------------
__global__ __launch_bounds__(256) void cfconv_lin1(const float* __restrict__ X,
                                                   const float* __restrict__ W,
                                                   float* __restrict__ Y) {
  __shared__ __align__(16) float wT[128 * 68];   // wT[k][c] = W[c0+c][k], pad 68
  __shared__ __align__(16) float xs[64 * 132];   // xs[r][k], pad 132
  const int tid = threadIdx.x;
  const int row0 = (blockIdx.x >> 1) * 64;
  const int c0 = (blockIdx.x & 1) * 64;
  for (int i = tid; i < 64 * 128; i += 256) {
    int c = i >> 7, k = i & 127;
    wT[k * 68 + c] = W[(c0 + c) * 128 + k];
  }
  for (int i = tid; i < 64 * 128; i += 256) {
    int r = i >> 7, k = i & 127;
    int row = row0 + r;
    xs[r * 132 + k] = (row < NNODES) ? X[row * 128 + k] : 0.f;
  }
  __syncthreads();
  const int c4 = (tid & 15) * 4;
  const int r4 = (tid >> 4) * 4;
  f32x4 a0 = {}, a1 = {}, a2 = {}, a3 = {};
#pragma unroll 4
  for (int k = 0; k < 128; ++k) {
    f32x4 wv = *(const f32x4*)&wT[k * 68 + c4];
    a0 += wv * xs[(r4 + 0) * 132 + k];
    a1 += wv * xs[(r4 + 1) * 132 + k];
    a2 += wv * xs[(r4 + 2) * 132 + k];
    a3 += wv * xs[(r4 + 3) * 132 + k];
  }
  const int row = row0 + r4;
  if (row + 0 < NNODES) *(f32x4*)&Y[(row + 0) * 128 + c0 + c4] = a0;
  if (row + 1 < NNODES) *(f32x4*)&Y[(row + 1) * 128 + c0 + c4] = a1;
  if (row + 2 < NNODES) *(f32x4*)&Y[(row + 2) * 128 + c0 + c4] = a2;
  if (row + 3 < NNODES) *(f32x4*)&Y[(row + 3) * 128 + c0 + c4] = a3;
}

// ------- K3 (fast path): out = (h1 + agg) @ W^T + b; reads ws, writes d_out --
__global__ __launch_bounds__(256) void cfconv_lin2_sc(const float* __restrict__ H1,
                                                      const float* __restrict__ AG,
                                                      const float* __restrict__ W,
                                                      const float* __restrict__ Bias,
                                                      float* __restrict__ OUT) {
  __shared__ __align__(16) float wT[128 * 68];
  __shared__ __align__(16) float xs[64 * 132];
  const int tid = threadIdx.x;
  const int row0 = (blockIdx.x >> 1) * 64;
  const int c0 = (blockIdx.x & 1) * 64;
  for (int i = tid; i < 64 * 128; i += 256) {
    int c = i >> 7, k = i & 127;
    wT[k * 68 + c] = W[(c0 + c) * 128 + k];
  }
  for (int i = tid; i < 64 * 128; i += 256) {
    int r = i >> 7, k = i & 127;
    int row = row0 + r;
    xs[r * 132 + k] = (row < NNODES)
        ? (H1[(size_t)row * 128 + k] + AG[(size_t)row * 128 + k]) : 0.f;
  }
  __syncthreads();
  const int c4 = (tid & 15) * 4;
  const int r4 = (tid >> 4) * 4;
  f32x4 a0 = {}, a1 = {}, a2 = {}, a3 = {};
#pragma unroll 4
  for (int k = 0; k < 128; ++k) {
    f32x4 wv = *(const f32x4*)&wT[k * 68 + c4];
    a0 += wv * xs[(r4 + 0) * 132 + k];
    a1 += wv * xs[(r4 + 1) * 132 + k];
    a2 += wv * xs[(r4 + 2) * 132 + k];
    a3 += wv * xs[(r4 + 3) * 132 + k];
  }
  const f32x4 bv = *(const f32x4*)&Bias[c0 + c4];
  a0 += bv; a1 += bv; a2 += bv; a3 += bv;
  const int row = row0 + r4;
  if (row + 0 < NNODES) *(f32x4*)&OUT[(size_t)(row + 0) * 128 + c0 + c4] = a0;
  if (row + 1 < NNODES) *(f32x4*)&OUT[(size_t)(row + 1) * 128 + c0 + c4] = a1;
  if (row + 2 < NNODES) *(f32x4*)&OUT[(size_t)(row + 2) * 128 + c0 + c4] = a2;
  if (row + 3 < NNODES) *(f32x4*)&OUT[(size_t)(row + 3) * 128 + c0 + c4] = a3;
}

// ------- K3 (mid path): in-place on d_out, full-width blocks (no aliasing) ---
__global__ __launch_bounds__(256) void cfconv_lin2_fw(const float* __restrict__ H1,
                                                      float* AO,
                                                      const float* __restrict__ W,
                                                      const float* __restrict__ Bias) {
  __shared__ __align__(16) float wT[128 * 132];
  __shared__ __align__(16) float xs[64 * 132];
  const int tid = threadIdx.x;
  const int row0 = blockIdx.x * 64;
  for (int i = tid; i < 128 * 128; i += 256) {
    int c = i >> 7, k = i & 127;
    wT[k * 132 + c] = W[c * 128 + k];
  }
  for (int i = tid; i < 64 * 128; i += 256) {
    int r = i >> 7, k = i & 127;
    int row = row0 + r;
    xs[r * 132 + k] = (row < NNODES) ? (H1[(size_t)row * 128 + k] + AO[(size_t)row * 128 + k]) : 0.f;
  }
  __syncthreads();
  const int c8 = (tid & 15) * 8;
  const int r4 = (tid >> 4) * 4;
  f32x4 a[4][2] = {};
#pragma unroll 2
  for (int k = 0; k < 128; ++k) {
    f32x4 w0 = *(const f32x4*)&wT[k * 132 + c8];
    f32x4 w1 = *(const f32x4*)&wT[k * 132 + c8 + 4];
#pragma unroll
    for (int r = 0; r < 4; ++r) {
      float x = xs[(r4 + r) * 132 + k];
      a[r][0] += w0 * x;
      a[r][1] += w1 * x;
    }
  }
  const f32x4 b0 = *(const f32x4*)&Bias[c8];
  const f32x4 b1 = *(const f32x4*)&Bias[c8 + 4];
#pragma unroll
  for (int r = 0; r < 4; ++r) {
    int row = row0 + r4 + r;
    if (row < NNODES) {
      *(f32x4*)&AO[(size_t)row * 128 + c8]     = a[r][0] + b0;
      *(f32x4*)&AO[(size_t)row * 128 + c8 + 4] = a[r][1] + b1;
    }
  }
}

// ---------------- sort-by-dst machinery --------------------------------------
__global__ void k_hist(const int* __restrict__ ei, int* __restrict__ cnt) {
  int e = blockIdx.x * 256 + threadIdx.x;
  if (e < NEDGES) atomicAdd(&cnt[ei[e]], 1);
}

// coalesced 3-phase scan over cnt[SCAN_N] (in-place -> exclusive prefix/cursor)
__global__ __launch_bounds__(256) void k_scanA(int* __restrict__ cnt,
                                               int* __restrict__ bsum) {
  __shared__ int sh[256];
  const int t = threadIdx.x;
  const int i = blockIdx.x * 256 + t;
  int v = cnt[i];
  sh[t] = v;
  __syncthreads();
  for (int off = 1; off < 256; off <<= 1) {
    int u = (t >= off) ? sh[t - off] : 0;
    __syncthreads();
    sh[t] += u;
    __syncthreads();
  }
  cnt[i] = sh[t] - v;  // exclusive within block
  if (t == 255) bsum[blockIdx.x] = sh[255];
}

__global__ __launch_bounds__(256) void k_scanB(int* __restrict__ bsum) {
  __shared__ int sh[256];
  const int t = threadIdx.x;
  int v = (t < SCAN_BLK) ? bsum[t] : 0;
  sh[t] = v;
  __syncthreads();
  for (int off = 1; off < 256; off <<= 1) {
    int u = (t >= off) ? sh[t - off] : 0;
    __syncthreads();
    sh[t] += u;
    __syncthreads();
  }
  if (t < SCAN_BLK) bsum[t] = sh[t] - v;  // exclusive block bases
}

__global__ __launch_bounds__(256) void k_scanC(int* __restrict__ cnt,
                                               const int* __restrict__ bsum) {
  int i = blockIdx.x * 256 + threadIdx.x;
  cnt[i] += bsum[blockIdx.x];
}

__global__ void k_scatter(const int* __restrict__ ei, int* __restrict__ cursor,
                          int* __restrict__ sorted) {
  int e = blockIdx.x * 256 + threadIdx.x;
  if (e < NEDGES) {
    int pos = atomicAdd(&cursor[ei[e]], 1);
    sorted[pos] = e;
  }
}

// ---------------- K2: edge-parallel, dst-sorted, 2-deep pipelined ------------
// Per wave-tile: 16 sorted edges. attr A-fragments load straight from global
// (no sA). Next tile's sorted/ei/ew/attr loads issue before current compute.
// Segmented-reduction epilogue (dsts non-decreasing) keeps atomics ~8x down.

#define LOADSET(S, TL)                                                         \
  {                                                                            \
    const int base_ = (TL) * 16;                                               \
    int sem_[4];                                                               \
    _Pragma("unroll") for (int r = 0; r < 4; ++r)                              \
        sem_[r] = sorted[base_ + lk * 4 + r];                                  \
    const int ser_ = sorted[base_ + lrow];                                     \
    _Pragma("unroll") for (int r = 0; r < 4; ++r) {                            \
      dst_##S[r] = ei[sem_[r]];                                                \
      src_##S[r] = ei[NEDGES + sem_[r]];                                       \
      cw_##S[r] = 0.5f * (__cosf(ew[sem_[r]] * PI_OVER_CUT) + 1.f);            \
    }                                                                          \
    const float* ar_ = attr + (size_t)ser_ * NG;                               \
    _Pragma("unroll") for (int jj = 0; jj < 4; ++jj) {                         \
      f32x2 v = *(const f32x2*)(ar_ + lk * 8 + jj * 2);                        \
      av0_##S[jj * 2] = f2bf(v.x);                                             \
      av0_##S[jj * 2 + 1] = f2bf(v.y);                                         \
    }                                                                          \
    _Pragma("unroll") for (int jj = 0; jj < 4; ++jj) {                         \
      int k_ = 32 + lk * 8 + jj * 2;                                           \
      f32x2 v = {0.f, 0.f};                                                    \
      if (k_ + 2 <= NG) v = *(const f32x2*)(ar_ + k_);                         \
      av1_##S[jj * 2] = f2bf(v.x);                                             \
      av1_##S[jj * 2 + 1] = f2bf(v.y);                                         \
    }                                                                          \
  }

#define COMPUTESET(S)                                                          \
  {                                                                            \
    float hv[8][4];                                                            \
    _Pragma("unroll") for (int t = 0; t < 8; ++t)                              \
      _Pragma("unroll") for (int r = 0; r < 4; ++r)                            \
        hv[t][r] = h1[(size_t)src_##S[r] * 128 + t * 16 + lrow];               \
    f32x4 acc[8] = {};                                                         \
    _Pragma("unroll") for (int t = 0; t < 8; ++t)                              \
      acc[t] = __builtin_amdgcn_mfma_f32_16x16x32_bf16(                        \
          av0_##S, B1[t * 64 + lane], acc[t], 0, 0, 0);                        \
    _Pragma("unroll") for (int t = 0; t < 8; ++t)                              \
      acc[t] = __builtin_amdgcn_mfma_f32_16x16x32_bf16(                        \
          av1_##S, B1[(8 + t) * 64 + lane], acc[t], 0, 0, 0);                  \
    _Pragma("unroll") for (int t = 0; t < 8; ++t) {                            \
      int f = t * 16 + lrow;                                                   \
      float bb = sb1[f];                                                       \
      _Pragma("unroll") for (int r = 0; r < 4; ++r) {                          \
        int row = lk * 4 + r;                                                  \
        float v = sp_shift(acc[t][r] + bb);                                    \
        int a = (row * 256 + f * 2) ^ ((row & 7) << 4);                        \
        *(short*)(sXw + a) = f2bf(v);                                          \
      }                                                                        \
    }                                                                          \
    f32x4 acc2[8] = {};                                                        \
    _Pragma("unroll") for (int s = 0; s < 4; ++s) {                            \
      int ab = (lrow * 256 + s * 64 + lk * 16) ^ ((lrow & 7) << 4);            \
      s16x8 av = *(const s16x8*)(sXw + ab);                                    \
      _Pragma("unroll") for (int t = 0; t < 8; ++t)                            \
        acc2[t] = __builtin_amdgcn_mfma_f32_16x16x32_bf16(                     \
            av, B2[(s * 8 + t) * 64 + lane], acc2[t], 0, 0, 0);                \
    }                                                                          \
    const int d0 = dst_##S[0], d3 = dst_##S[3];                                \
    const bool b1f = dst_##S[1] != d0, b2f = dst_##S[2] != dst_##S[1],         \
               b3f = d3 != dst_##S[2];                                         \
    const bool allsame = !(b1f | b2f | b3f);                                   \
    const int next_head = __shfl(d0, (lane + 16) & 63);                        \
    const bool tor = (lk < 3) && (next_head == d3);                            \
    const int td0 = __shfl(d3, lrow);                                          \
    const int td1 = __shfl(d3, lrow + 16);                                     \
    const int td2 = __shfl(d3, lrow + 32);                                     \
    const bool m0 = (lk >= 1) && (td0 == d0);                                  \
    const bool m1 = (lk >= 2) && (td1 == d0);                                  \
    const bool m2 = (lk >= 3) && (td2 == d0);                                  \
    const bool emit_head = !(allsame && tor);                                  \
    const bool emit_tail = (!allsame) && !tor;                                 \
    const bool mid1 = b1f && b2f, mid2 = b2f && b3f,                           \
               mid12 = b1f && (!b2f) && b3f;                                   \
    _Pragma("unroll") for (int t = 0; t < 8; ++t) {                            \
      int f = t * 16 + lrow;                                                   \
      float bb = sb2[f];                                                       \
      float v0 = sp_shift(acc2[t][0] + bb) * cw_##S[0] * hv[t][0];             \
      float v1 = sp_shift(acc2[t][1] + bb) * cw_##S[1] * hv[t][1];             \
      float v2 = sp_shift(acc2[t][2] + bb) * cw_##S[2] * hv[t][2];             \
      float v3 = sp_shift(acc2[t][3] + bb) * cw_##S[3] * hv[t][3];             \
      float head_sum = v0 + (b1f ? 0.f : v1 + (b2f ? 0.f : v2 + (b3f ? 0.f : v3))); \
      float tail_sum = v3 + (b3f ? 0.f : v2 + (b2f ? 0.f : v1 + (b1f ? 0.f : v0))); \
      float ts0 = __shfl(tail_sum, lrow);                                      \
      float ts1 = __shfl(tail_sum, lrow + 16);                                 \
      float ts2 = __shfl(tail_sum, lrow + 32);                                 \
      float carry = (m0 ? ts0 : 0.f) + (m1 ? ts1 : 0.f) + (m2 ? ts2 : 0.f);    \
      if (emit_head) atomicAdd(&agg[(size_t)d0 * 128 + f], head_sum + carry);  \
      if (emit_tail) atomicAdd(&agg[(size_t)d3 * 128 + f], tail_sum);          \
      if (mid1) atomicAdd(&agg[(size_t)dst_##S[1] * 128 + f], v1);             \
      if (mid2) atomicAdd(&agg[(size_t)dst_##S[2] * 128 + f], v2);             \
      if (mid12) atomicAdd(&agg[(size_t)dst_##S[1] * 128 + f], v1 + v2);       \
    }                                                                          \
  }

__global__ __launch_bounds__(256, 2) void cfconv_edge_sorted(
    const int* __restrict__ ei, const float* __restrict__ ew,
    const float* __restrict__ attr,
    const float* __restrict__ w1, const float* __restrict__ b1,
    const float* __restrict__ w2, const float* __restrict__ b2,
    const float* __restrict__ h1, const int* __restrict__ sorted,
    float* __restrict__ agg) {
  __shared__ __align__(16) short sB1[8192];    // W1^T frags: [s<2][t<8][lane][8]
  __shared__ __align__(16) short sB2[16384];   // W2^T frags: [s<4][t<8][lane][8]
  __shared__ __align__(16) short sX[4][2048];  // per-wave X tile [16][128] bf16, swizzled
  __shared__ float sb1[128], sb2[128];
  const int tid = threadIdx.x;
  if (tid < 128) { sb1[tid] = b1[tid]; sb2[tid] = b2[tid]; }
  // B-operand fragment layout: lane l holds B[k=(l>>4)*8+j][n=(l&15)]
  for (int i = tid; i < 8192; i += 256) {
    int j = i & 7, l = (i >> 3) & 63, t = (i >> 9) & 7, s = i >> 12;
    int g = s * 32 + (l >> 4) * 8 + j;
    int f = t * 16 + (l & 15);
    sB1[i] = f2bf(g < NG ? w1[f * NG + g] : 0.f);
  }
  for (int i = tid; i < 16384; i += 256) {
    int j = i & 7, l = (i >> 3) & 63, t = (i >> 9) & 7, s = (i >> 12) & 3;
    int k = s * 32 + (l >> 4) * 8 + j;
    int f = t * 16 + (l & 15);
    sB2[i] = f2bf(w2[f * 128 + k]);
  }
  __syncthreads();   // weights ready; read-only from here on
  const int lane = tid & 63;
  const int wave = tid >> 6;
  const int lrow = lane & 15;
  const int lk = lane >> 4;
  const s16x8* B1 = (const s16x8*)sB1;
  const s16x8* B2 = (const s16x8*)sB2;
  char* sXw = (char*)sX[wave];
  const int gw0 = blockIdx.x * 4 + wave;
  const int gstride = gridDim.x * 4;

  s16x8 av0_A, av1_A, av0_B, av1_B;
  int dst_A[4], src_A[4], dst_B[4], src_B[4];
  float cw_A[4], cw_B[4];

  int tl = gw0;
  if (tl < NTILES) LOADSET(A, tl);
  while (tl < NTILES) {
    int n1 = tl + gstride;
    if (n1 < NTILES) LOADSET(B, n1);
    COMPUTESET(A);
    tl = n1;
    if (tl >= NTILES) break;
    int n2 = tl + gstride;
    if (n2 < NTILES) LOADSET(A, n2);
    COMPUTESET(B);
    tl = n2;
  }
}

// ---------------- last-resort fallback (unsorted, plain atomics) -------------
__global__ __launch_bounds__(256) void cfconv_edge_atomic(
    const int* __restrict__ ei, const float* __restrict__ ew,
    const float* __restrict__ attr,
    const float* __restrict__ w1, const float* __restrict__ b1,
    const float* __restrict__ w2, const float* __restrict__ b2,
    const float* __restrict__ h1, float* __restrict__ agg) {
  __shared__ __align__(16) short sB1[8192];
  __shared__ __align__(16) short sB2[16384];
  __shared__ __align__(16) short sX[4][2048];
  __shared__ float sb1[128], sb2[128];
  const int tid = threadIdx.x;
  if (tid < 128) { sb1[tid] = b1[tid]; sb2[tid] = b2[tid]; }
  for (int i = tid; i < 8192; i += 256) {
    int j = i & 7, l = (i >> 3) & 63, t = (i >> 9) & 7, s = i >> 12;
    int g = s * 32 + (l >> 4) * 8 + j;
    int f = t * 16 + (l & 15);
    sB1[i] = f2bf(g < NG ? w1[f * NG + g] : 0.f);
  }
  for (int i = tid; i < 16384; i += 256) {
    int j = i & 7, l = (i >> 3) & 63, t = (i >> 9) & 7, s = (i >> 12) & 3;
    int k = s * 32 + (l >> 4) * 8 + j;
    int f = t * 16 + (l & 15);
    sB2[i] = f2bf(w2[f * 128 + k]);
  }
  __syncthreads();
  const int lane = tid & 63;
  const int wave = tid >> 6;
  const int lrow = lane & 15;
  const int lk = lane >> 4;
  const s16x8* B1 = (const s16x8*)sB1;
  const s16x8* B2 = (const s16x8*)sB2;
  char* sXw = (char*)sX[wave];
  const int gw0 = blockIdx.x * 4 + wave;
  const int gstride = gridDim.x * 4;
  for (int wt = gw0; wt < NTILES; wt += gstride) {
    const int e0 = wt * 16;
    int dst[4], src[4];
    float cw[4];
#pragma unroll
    for (int r = 0; r < 4; ++r) {
      int e = e0 + lk * 4 + r;
      dst[r] = ei[e];
      src[r] = ei[NEDGES + e];
      cw[r] = 0.5f * (__cosf(ew[e] * PI_OVER_CUT) + 1.f);
    }
    float hv[8][4];
#pragma unroll
    for (int t = 0; t < 8; ++t)
#pragma unroll
      for (int r = 0; r < 4; ++r)
        hv[t][r] = h1[(size_t)src[r] * 128 + t * 16 + lrow];
    const float* ar = attr + (size_t)(e0 + lrow) * NG;
    s16x8 av0, av1;
#pragma unroll
    for (int jj = 0; jj < 4; ++jj) {
      f32x2 v = *(const f32x2*)(ar + lk * 8 + jj * 2);
      av0[jj * 2] = f2bf(v.x); av0[jj * 2 + 1] = f2bf(v.y);
    }
#pragma unroll
    for (int jj = 0; jj < 4; ++jj) {
      int k = 32 + lk * 8 + jj * 2;
      f32x2 v = {0.f, 0.f};
      if (k + 2 <= NG) v = *(const f32x2*)(ar + k);
      av1[jj * 2] = f2bf(v.x); av1[jj * 2 + 1] = f2bf(v.y);
    }
    f32x4 acc[8] = {};
#pragma unroll
    for (int t = 0; t < 8; ++t)
      acc[t] = __builtin_amdgcn_mfma_f32_16x16x32_bf16(av0, B1[t * 64 + lane], acc[t], 0, 0, 0);
#pragma unroll
    for (int t = 0; t < 8; ++t)
      acc[t] = __builtin_amdgcn_mfma_f32_16x16x32_bf16(av1, B1[(8 + t) * 64 + lane], acc[t], 0, 0, 0);
#pragma unroll
    for (int t = 0; t < 8; ++t) {
      int f = t * 16 + lrow;
      float bb = sb1[f];
#pragma unroll
      for (int r = 0; r < 4; ++r) {
        int row = lk * 4 + r;
        float v = sp_shift(acc[t][r] + bb);
        int a = (row * 256 + f * 2) ^ ((row & 7) << 4);
        *(short*)(sXw + a) = f2bf(v);
      }
    }
    f32x4 acc2[8] = {};
#pragma unroll
    for (int s = 0; s < 4; ++s) {
      int ab = (lrow * 256 + s * 64 + lk * 16) ^ ((lrow & 7) << 4);
      s16x8 av = *(const s16x8*)(sXw + ab);
#pragma unroll
      for (int t = 0; t < 8; ++t)
        acc2[t] = __builtin_amdgcn_mfma_f32_16x16x32_bf16(av, B2[(s * 8 + t) * 64 + lane], acc2[t], 0, 0, 0);
    }
#pragma unroll
    for (int t = 0; t < 8; ++t) {
      int f = t * 16 + lrow;
      float bb = sb2[f];
#pragma unroll
      for (int r = 0; r < 4; ++r) {
        float Wv = sp_shift(acc2[t][r] + bb) * cw[r];
        atomicAdd(&agg[(size_t)dst[r] * 128 + f], Wv * hv[t][r]);
      }
    }
  }
}

extern "C" void kernel_launch(void* const* d_in, const int* in_sizes, int n_in,
                              void* d_out, int out_size, void* d_ws, size_t ws_size,
                              hipStream_t stream) {
  const float* h      = (const float*)d_in[0];
  const int*   ei     = (const int*)d_in[1];
  const float* ew     = (const float*)d_in[2];
  const float* attr   = (const float*)d_in[3];
  const float* lin1_w = (const float*)d_in[4];
  const float* nn_w1  = (const float*)d_in[5];
  const float* nn_b1  = (const float*)d_in[6];
  const float* nn_w2  = (const float*)d_in[7];
  const float* nn_b2  = (const float*)d_in[8];
  const float* lin2_w = (const float*)d_in[9];
  const float* lin2_b = (const float*)d_in[10];
  float* out = (float*)d_out;

  const int rb2 = ((NNODES + 63) / 64) * 2;      // split-col GEMM grid
  const int rbF = (NNODES + 63) / 64;            // full-width GEMM grid

  // ws layout: cnt[SCAN_N] | bsum[256] | sorted[NEDGES] | h1 | (agg)
  const size_t off_bs     = (size_t)SCAN_N * 4;                  // 200704
  const size_t off_sorted = off_bs + 1024;                       // 201728
  const size_t off_h1     = (off_sorted + (size_t)NEDGES * 4 + 127) & ~(size_t)127;
  const size_t off_agg    = off_h1 + (size_t)NNODES * 128 * 4;
  const size_t need_mid   = off_agg;                             // sort + h1
  const size_t need_full  = off_agg + (size_t)NNODES * 128 * 4;  // + agg

  if (ws_size >= need_mid) {
    int* cnt    = (int*)d_ws;
    int* bsum   = (int*)((char*)d_ws + off_bs);
    int* sorted = (int*)((char*)d_ws + off_sorted);
    float* h1   = (float*)((char*)d_ws + off_h1);
    const bool full = (ws_size >= need_full);
    float* agg  = full ? (float*)((char*)d_ws + off_agg) : out;

    hipMemsetAsync(cnt, 0, (size_t)SCAN_N * 4, stream);
    hipMemsetAsync(agg, 0, (size_t)NNODES * 128 * 4, stream);
    k_hist<<<(NEDGES + 255) / 256, 256, 0, stream>>>(ei, cnt);
    k_scanA<<<SCAN_BLK, 256, 0, stream>>>(cnt, bsum);
    k_scanB<<<1, 256, 0, stream>>>(bsum);
    k_scanC<<<SCAN_BLK, 256, 0, stream>>>(cnt, bsum);
    k_scatter<<<(NEDGES + 255) / 256, 256, 0, stream>>>(ei, cnt, sorted);
    cfconv_lin1<<<rb2, 256, 0, stream>>>(h, lin1_w, h1);
    cfconv_edge_sorted<<<512, 256, 0, stream>>>(ei, ew, attr, nn_w1, nn_b1,
                                                nn_w2, nn_b2, h1, sorted, agg);
    if (full)
      cfconv_lin2_sc<<<rb2, 256, 0, stream>>>(h1, agg, lin2_w, lin2_b, out);
    else
      cfconv_lin2_fw<<<rbF, 256, 0, stream>>>(h1, out, lin2_w, lin2_b);
  } else {
    float* h1 = (float*)d_ws;
    hipMemsetAsync(out, 0, (size_t)NNODES * 128 * 4, stream);
    cfconv_lin1<<<rb2, 256, 0, stream>>>(h, lin1_w, h1);
    cfconv_edge_atomic<<<512, 256, 0, stream>>>(ei, ew, attr, nn_w1, nn_b1,
                                                nn_w2, nn_b2, h1, out);
    cfconv_lin2_fw<<<rbF, 256, 0, stream>>>(h1, out, lin2_w, lin2_b);
  }
}